// Round 1
// baseline (36.414 us; speedup 1.0000x reference)
//
#include <hip/hip_runtime.h>
#include <math.h>

#define GS 14          // grid size S
#define NCELL 196      // S*S
#define NCLS 90
#define CH 95          // 5 + NUM_CLS

// One block per image. 256 threads = 4 waves of 64.
__global__ __launch_bounds__(256) void yolo_loss_main(
    const float* __restrict__ p, const float* __restrict__ g,
    float* __restrict__ ws, int B)
{
    int b = blockIdx.x;
    if (b >= B) return;
    const float* pb = p + (size_t)b * NCELL * CH;
    const float* gb = g + (size_t)b * NCELL * CH;

    __shared__ float sp[NCELL][5];   // pred boxes (local coords + conf)
    __shared__ float st[NCELL][5];   // target boxes + conf
    __shared__ int   svalid[NCELL];  // compacted valid cell indices
    __shared__ int   scount;
    __shared__ int   shit[NCELL];    // hit mask (pred selected by a valid target)
    __shared__ float sred[4];

    const int tid  = threadIdx.x;
    const int wave = tid >> 6;
    const int lane = tid & 63;

    // Stage first 5 channels of pred/target into LDS.
    for (int i = tid; i < NCELL * 5; i += 256) {
        int c = i / 5, j = i - c * 5;
        sp[c][j] = pb[c * CH + j];
        st[c][j] = gb[c * CH + j];
    }
    for (int i = tid; i < NCELL; i += 256) shit[i] = 0;
    __syncthreads();

    // Deterministic compaction of valid cells (conf > 0), ascending order.
    if (tid == 0) {
        int cnt = 0;
        for (int c = 0; c < NCELL; ++c)
            if (st[c][4] > 0.0f) svalid[cnt++] = c;
        scount = cnt;
    }
    __syncthreads();
    const int count = scount;

    float xy_acc = 0.0f, con_acc = 0.0f;

    // One wave per valid target; each lane covers preds lane, lane+64, ...
    for (int vt = wave; vt < count; vt += 4) {
        const int t = svalid[vt];
        // target xy in global coords, exactly like reference: col/S + x/S
        const float tx = __fadd_rn(__fdiv_rn((float)(t % GS), (float)GS),
                                   __fdiv_rn(st[t][0], (float)GS));
        const float ty = __fadd_rn(__fdiv_rn((float)(t / GS), (float)GS),
                                   __fdiv_rn(st[t][1], (float)GS));
        const float tw = st[t][2], th = st[t][3];
        const float twth = __fmul_rn(tw, th);

        float bi = -INFINITY;
        int   bidx = 0x7fffffff;
        for (int pp = lane; pp < NCELL; pp += 64) {
            const float px = sp[pp][0], py = sp[pp][1];
            const float pw = sp[pp][2], ph = sp[pp][3];
            // Faithful IEEE per-op order (no FMA contraction): ref's buggy
            // clamp-after-product IoU; union can be tiny/negative -> huge iou.
            const float dx = fabsf(__fsub_rn(tx, px));
            const float dy = fabsf(__fsub_rn(ty, py));
            const float sw = __fmul_rn(__fadd_rn(tw, pw), 0.5f);
            const float sh = __fmul_rn(__fadd_rn(th, ph), 0.5f);
            const float inter = fmaxf(__fmul_rn(__fsub_rn(sw, dx),
                                                __fsub_rn(sh, dy)), 0.0f);
            const float uni = __fsub_rn(__fadd_rn(twth, __fmul_rn(pw, ph)), inter);
            const float iou = __fdiv_rn(inter, uni);
            // first-occurrence max (per-lane pp ascends; strict > keeps earliest)
            if (iou > bi || (iou == bi && pp < bidx)) { bi = iou; bidx = pp; }
        }
        // wave-wide max/argmax butterfly with smaller-index tie-break
        for (int off = 32; off; off >>= 1) {
            const float oi  = __shfl_xor(bi, off);
            const int   oid = __shfl_xor(bidx, off);
            if (oi > bi || (oi == bi && oid < bidx)) { bi = oi; bidx = oid; }
        }
        if (lane == 0) {
            const float d0 = __fsub_rn(sp[bidx][0], tx);
            const float d1 = __fsub_rn(sp[bidx][1], ty);
            xy_acc += __fadd_rn(__fmul_rn(d0, d0), __fmul_rn(d1, d1));
            const float cc = __fsub_rn(__fmul_rn(sp[bidx][4], bi), 1.0f);
            con_acc += __fmul_rn(cc, cc);
            shit[bidx] = 1;   // benign same-value race across waves
        }
    }
    __syncthreads();

    // no-object confidence loss (only for images containing >=1 object)
    float nocon_acc = 0.0f;
    if (count > 0) {
        for (int pp = tid; pp < NCELL; pp += 256) {
            if (!shit[pp]) {
                const float c = sp[pp][4];
                nocon_acc += c * c;
            }
        }
    }

    // class loss over valid cells: sum (p_cls - g_cls)^2
    float cls_acc = 0.0f;
    const int totalc = count * NCLS;
    for (int i = tid; i < totalc; i += 256) {
        const int vt = i / NCLS, j = i - vt * NCLS;
        const int t = svalid[vt];
        const float d = pb[t * CH + 5 + j] - gb[t * CH + 5 + j];
        cls_acc += d * d;
    }

    // per-thread total with lambda weights (xy doubled per original)
    float tot = 10.0f * xy_acc + con_acc + 0.5f * nocon_acc + cls_acc;
    for (int off = 32; off; off >>= 1) tot += __shfl_xor(tot, off);
    if (lane == 0) sred[wave] = tot;
    __syncthreads();
    if (tid == 0) ws[b] = sred[0] + sred[1] + sred[2] + sred[3];
}

__global__ __launch_bounds__(256) void yolo_loss_reduce(
    const float* __restrict__ ws, float* __restrict__ out, int B)
{
    const int tid = threadIdx.x;
    float s = 0.0f;
    for (int i = tid; i < B; i += 256) s += ws[i];
    for (int off = 32; off; off >>= 1) s += __shfl_xor(s, off);
    __shared__ float sr[4];
    if ((tid & 63) == 0) sr[tid >> 6] = s;
    __syncthreads();
    if (tid == 0) out[0] = (sr[0] + sr[1] + sr[2] + sr[3]) / (float)B;
}

extern "C" void kernel_launch(void* const* d_in, const int* in_sizes, int n_in,
                              void* d_out, int out_size, void* d_ws, size_t ws_size,
                              hipStream_t stream) {
    const float* p = (const float*)d_in[0];
    const float* g = (const float*)d_in[1];
    float* out = (float*)d_out;
    float* ws  = (float*)d_ws;
    const int B = in_sizes[0] / (NCELL * CH);   // 1024

    yolo_loss_main<<<B, 256, 0, stream>>>(p, g, ws, B);
    yolo_loss_reduce<<<1, 256, 0, stream>>>(ws, out, B);
}

// Round 2
// 32.330 us; speedup vs baseline: 1.1263x; 1.1263x over previous
//
#include <hip/hip_runtime.h>
#include <math.h>

#define GS 14          // grid size S
#define NCELL 196      // S*S
#define NCLS 90
#define CH 95          // 5 + NUM_CLS

// One block per image. 256 threads = 4 waves of 64.
// Fused: per-block partial losses are atomically accumulated (pre-scaled by
// 1/B, exact for B=1024) into d_out[0], which is zeroed by an async memset
// captured in the same graph. Only summation ORDER varies run-to-run (ulp-level).
__global__ __launch_bounds__(256) void yolo_loss_fused(
    const float* __restrict__ p, const float* __restrict__ g,
    float* __restrict__ out, float inv_b)
{
    const int b = blockIdx.x;
    const float* pb = p + (size_t)b * NCELL * CH;
    const float* gb = g + (size_t)b * NCELL * CH;

    __shared__ float sp[NCELL][5];   // pred boxes (local coords + conf)
    __shared__ float st[NCELL][5];   // target boxes + conf
    __shared__ int   svalid[NCELL];  // compacted valid cell indices (ascending)
    __shared__ unsigned long long smask[4];
    __shared__ int   shit[NCELL];    // pred selected by some valid target
    __shared__ float sred[4];

    const int tid  = threadIdx.x;
    const int wave = tid >> 6;
    const int lane = tid & 63;

    // ---- Stage first 5 channels; one thread per cell (contiguous 20B run) ----
    bool v = false;
    if (tid < NCELL) {
        const float* pr = pb + tid * CH;
        const float* gr = gb + tid * CH;
        float g4 = gr[4];
        #pragma unroll
        for (int j = 0; j < 4; ++j) { sp[tid][j] = pr[j]; st[tid][j] = gr[j]; }
        sp[tid][4] = pr[4];
        st[tid][4] = g4;
        shit[tid] = 0;
        v = g4 > 0.0f;
    }
    // ---- Ballot-based parallel compaction (ascending cell order) ----
    const unsigned long long m = __ballot(v);
    if (lane == 0) smask[wave] = m;
    __syncthreads();

    int base = 0;
    #pragma unroll
    for (int w = 0; w < 4; ++w) if (w < wave) base += __popcll(smask[w]);
    const int count = __popcll(smask[0]) + __popcll(smask[1]) +
                      __popcll(smask[2]) + __popcll(smask[3]);
    if (v) {
        const int pos = base + __popcll(m & ((1ull << lane) - 1ull));
        svalid[pos] = tid;
    }
    __syncthreads();

    float xy_acc = 0.0f, con_acc = 0.0f;

    // ---- One wave per valid target; lanes stride over the 196 preds ----
    for (int vt = wave; vt < count; vt += 4) {
        const int t = svalid[vt];
        // target xy in global coords, exactly like reference: col/S + x/S
        const float tx = __fadd_rn(__fdiv_rn((float)(t % GS), (float)GS),
                                   __fdiv_rn(st[t][0], (float)GS));
        const float ty = __fadd_rn(__fdiv_rn((float)(t / GS), (float)GS),
                                   __fdiv_rn(st[t][1], (float)GS));
        const float tw = st[t][2], th = st[t][3];
        const float twth = __fmul_rn(tw, th);

        float bi = -INFINITY;
        int   bidx = 0x7fffffff;
        for (int pp = lane; pp < NCELL; pp += 64) {
            const float px = sp[pp][0], py = sp[pp][1];
            const float pw = sp[pp][2], ph = sp[pp][3];
            // Faithful IEEE per-op order (no FMA contraction): ref's buggy
            // clamp-after-product IoU; union can be tiny/negative -> huge iou.
            const float dx = fabsf(__fsub_rn(tx, px));
            const float dy = fabsf(__fsub_rn(ty, py));
            const float sw = __fmul_rn(__fadd_rn(tw, pw), 0.5f);
            const float sh = __fmul_rn(__fadd_rn(th, ph), 0.5f);
            const float inter = fmaxf(__fmul_rn(__fsub_rn(sw, dx),
                                                __fsub_rn(sh, dy)), 0.0f);
            const float uni = __fsub_rn(__fadd_rn(twth, __fmul_rn(pw, ph)), inter);
            const float iou = __fdiv_rn(inter, uni);
            if (iou > bi || (iou == bi && pp < bidx)) { bi = iou; bidx = pp; }
        }
        // wave-wide max/argmax butterfly, smaller-index tie-break (first occurrence)
        for (int off = 32; off; off >>= 1) {
            const float oi  = __shfl_xor(bi, off);
            const int   oid = __shfl_xor(bidx, off);
            if (oi > bi || (oi == bi && oid < bidx)) { bi = oi; bidx = oid; }
        }
        if (lane == 0) {
            const float d0 = __fsub_rn(sp[bidx][0], tx);
            const float d1 = __fsub_rn(sp[bidx][1], ty);
            xy_acc += __fadd_rn(__fmul_rn(d0, d0), __fmul_rn(d1, d1));
            const float cc = __fsub_rn(__fmul_rn(sp[bidx][4], bi), 1.0f);
            con_acc += __fmul_rn(cc, cc);
            shit[bidx] = 1;   // benign same-value race across waves
        }
    }
    __syncthreads();

    // ---- no-object confidence loss (only for images with >=1 object) ----
    float nocon_acc = 0.0f;
    if (count > 0 && tid < NCELL) {
        if (!shit[tid]) {
            const float c = sp[tid][4];
            nocon_acc = c * c;
        }
    }

    // ---- class loss over valid cells ----
    float cls_acc = 0.0f;
    const int totalc = count * NCLS;
    for (int i = tid; i < totalc; i += 256) {
        const int vt = i / NCLS, j = i - vt * NCLS;
        const int t = svalid[vt];
        const float d = pb[t * CH + 5 + j] - gb[t * CH + 5 + j];
        cls_acc += d * d;
    }

    // ---- block reduction + single atomic per block ----
    float tot = 10.0f * xy_acc + con_acc + 0.5f * nocon_acc + cls_acc;
    for (int off = 32; off; off >>= 1) tot += __shfl_xor(tot, off);
    if (lane == 0) sred[wave] = tot;
    __syncthreads();
    if (tid == 0) {
        const float bl = sred[0] + sred[1] + sred[2] + sred[3];
        atomicAdd(out, bl * inv_b);   // inv_b = 1/1024: exact scaling (pow2)
    }
}

extern "C" void kernel_launch(void* const* d_in, const int* in_sizes, int n_in,
                              void* d_out, int out_size, void* d_ws, size_t ws_size,
                              hipStream_t stream) {
    const float* p = (const float*)d_in[0];
    const float* g = (const float*)d_in[1];
    float* out = (float*)d_out;
    const int B = in_sizes[0] / (NCELL * CH);   // 1024

    hipMemsetAsync(out, 0, sizeof(float), stream);   // graph-capturable
    yolo_loss_fused<<<B, 256, 0, stream>>>(p, g, out, 1.0f / (float)B);
}